// Round 8
// baseline (112.528 us; speedup 1.0000x reference)
//
#include <hip/hip_runtime.h>

// Shapes: B=256, N=P=32, OBS=96, ACT=32, DIN=DOUT=128, DF1=64, DF2=32
#define VAL_SZ  (256*32*32*32)
#define W_OFF   VAL_SZ
#define WP_OFF  (VAL_SZ + 256*32*32)

// packed bf16 weights in ws (ushort offsets); B-frag order
#define PK_WV   0
#define PK_WVP  16384
#define PK_WQ   32768        // pre-scaled by 1/sqrt(128)
#define PK_WK   49152
#define PK_WQP  65536        // pre-scaled by 1/sqrt(128)
#define PK_WKP  81920
#define PK_WF1  98304        // 256x64 (kt 0..7, nt 0..3)
#define PK_WF2  114688       // 64x32  (kt 0..1, nt 0..1)

typedef short  bf16x8 __attribute__((ext_vector_type(8)));
typedef float  f32x4  __attribute__((ext_vector_type(4)));

#define MFMA(a, b, c) __builtin_amdgcn_mfma_f32_16x16x32_bf16(a, b, c, 0, 0, 0)

static __device__ __forceinline__ unsigned short f2bf(float f) {
    union { float f; unsigned u; } v; v.f = f;
    unsigned r = (v.u + 0x7FFF + ((v.u >> 16) & 1)) >> 16;
    return (unsigned short)r;
}
static __device__ __forceinline__ float bf2f(unsigned short u) {
    union { unsigned u; float f; } v; v.u = ((unsigned)u) << 16;
    return v.f;
}
static __device__ __forceinline__ float fast_tanh(float x) {
    x = fminf(fmaxf(x, -12.0f), 12.0f);
    float e = __expf(2.0f * x);
    return (e - 1.0f) / (e + 1.0f);
}

// A-frag (or B-frag from transposed row-major) from bf16 LDS; stride mult of 8.
static __device__ __forceinline__ bf16x8 afrag(const unsigned short* Mb, int stride,
                                               int row0, int kt) {
    int lane = threadIdx.x & 63;
    return *(const bf16x8*)(Mb + (row0 + (lane & 15)) * stride + kt * 32 + (lane >> 4) * 8);
}

// B-frag from packed global weights (single 16B load, L2-resident)
static __device__ __forceinline__ bf16x8 bfrag_pk(const unsigned short* base, int NT,
                                                  int kt, int nt) {
    int lane = threadIdx.x & 63;
    return *(const bf16x8*)(base + (((kt * NT + nt) * 64) + lane) * 8);
}

// ---------------------------------------------------------------------------
// Kernel 0 (lite): pure transpose/convert pack of all 8 weight matrices into
// bf16 B-fragment order. No GEMM. 14592 lane-slots -> 57 blocks x 256.
// ---------------------------------------------------------------------------
__global__ __launch_bounds__(256) void pack_lite(
    const float* __restrict__ Wk, const float* __restrict__ Wq,
    const float* __restrict__ Wv, const float* __restrict__ Wkp,
    const float* __restrict__ Wqp, const float* __restrict__ Wvp,
    const float* __restrict__ Wf1, const float* __restrict__ Wf2,
    unsigned short* __restrict__ pk)
{
    const float scale = 0.08838834764831845f;     // 1/sqrt(128)
    int gid = blockIdx.x * 256 + threadIdx.x;
    if (gid >= 14592) return;

    const float* W; int off, NT, ldn; float s = 1.0f;
    int r;
    if (gid < 12288) {                 // six 128x128 matrices
        int mat = gid >> 11;           // 0..5
        r = gid & 2047;
        NT = 8; ldn = 128;
        switch (mat) {
            case 0: W = Wv;  off = PK_WV;  break;
            case 1: W = Wvp; off = PK_WVP; break;
            case 2: W = Wq;  off = PK_WQ;  s = scale; break;
            case 3: W = Wk;  off = PK_WK;  break;
            case 4: W = Wqp; off = PK_WQP; s = scale; break;
            default: W = Wkp; off = PK_WKP; break;
        }
    } else if (gid < 14336) {          // Wf1 256x64
        r = gid - 12288; W = Wf1; off = PK_WF1; NT = 4; ldn = 64;
    } else {                           // Wf2 64x32
        r = gid - 14336; W = Wf2; off = PK_WF2; NT = 2; ldn = 32;
    }
    int lane = r & 63;
    int l16 = lane & 15, quad = lane >> 4;
    int ktnt = r >> 6;
    int nt = ktnt % NT, kt = ktnt / NT;
    int n = nt * 16 + l16;
    int kb = kt * 32 + quad * 8;
    union { unsigned short u[8]; bf16x8 v; } o;
#pragma unroll
    for (int j = 0; j < 8; ++j) o.u[j] = f2bf(W[(kb + j) * ldn + n] * s);
    *(bf16x8*)(pk + off + (ktnt * 64 + lane) * 8) = o.v;
}

// ---------------------------------------------------------------------------
// Kernel A: fused per-batch forward. grid 256 x 1024 threads (16 waves),
// 7 barriers, wave-specialized.  Key refactor vs prior round:
//   F[a] = (weight@VA1 + wp@AV1)/N with VA1 = va@Wf1_top, AV1 = avp@Wf1_bot
// (associativity) -- removes NF staging + K=256 GEMM + 1 barrier.
// LDS 65024 B:
//  OA   @0      8704  oa [32x136]
//  OP   @8704   8704  op -> oap (PB)
//  TD   @17408  8704  delta [32x136] -> AVr (avp row-major, PC)
//  VAr  @26112  8704  va row-major    -> SB2 @26112 [32x40], WPB @28672 [32x40]
//  QL   @34816  8704  q -> qp         -> FP [32x66 f32]
//  KL   @43520  8704  k -> kp         -> GP [32x67 f32]
//  VA1T @52224  5120  (va@Wf1_top)^T [64x40]
//  AV1T @57344  5120  (avp@Wf1_bot)^T [64x40]
//  SB1  @62464  2560  scores -> weight bf16 [a][j] stride 40
// ---------------------------------------------------------------------------
__global__ __launch_bounds__(1024) void critic_fused(
    const float* __restrict__ states, const float* __restrict__ policies,
    const float* __restrict__ actions, const float* __restrict__ states_p,
    const float* __restrict__ actions_p,
    const unsigned short* __restrict__ pk, float* __restrict__ out)
{
    __shared__ __align__(16) unsigned char SM[65024];
    unsigned short* OA   = (unsigned short*)(SM + 0);
    unsigned short* OP   = (unsigned short*)(SM + 8704);
    unsigned short* TD   = (unsigned short*)(SM + 17408);
    unsigned short* AVr  = (unsigned short*)(SM + 17408);
    unsigned short* VAr  = (unsigned short*)(SM + 26112);
    unsigned short* SB2  = (unsigned short*)(SM + 26112);   // [p][n] stride 40
    unsigned short* WPB  = (unsigned short*)(SM + 28672);   // wp [n][p] stride 40
    unsigned short* QL   = (unsigned short*)(SM + 34816);
    float*          FP   = (float*)(SM + 34816);            // F [a][66]
    unsigned short* KL   = (unsigned short*)(SM + 43520);
    float*          GP   = (float*)(SM + 43520);            // G [i][67]
    unsigned short* VA1T = (unsigned short*)(SM + 52224);   // [h][j] stride 40
    unsigned short* AV1T = (unsigned short*)(SM + 57344);   // [h][p] stride 40
    unsigned short* SB1  = (unsigned short*)(SM + 62464);   // [a][j] stride 40

    const int tid = threadIdx.x;
    const int b = blockIdx.x;
    const int lane = tid & 63, wv = tid >> 6;              // wv 0..15
    const int l16 = lane & 15, quad = lane >> 4;
    const float invN = 1.0f / 32.0f;
    const f32x4 Z = {0.f, 0.f, 0.f, 0.f};

    // ---- P0: load oa -> OA, op -> OP (bf16) ----
    {
        const float* st = states   + (size_t)b * 3072;
        const float* ac = actions  + (size_t)b * 1024;
        const float* po = policies + (size_t)b * 1024;
#pragma unroll
        for (int k = 0; k < 4; ++k) {
            int idx = tid + k * 1024;
            int n = idx >> 7, d = idx & 127;
            float sv, pv;
            if (d < 96) { sv = st[n * 96 + d]; pv = sv; }
            else        { sv = ac[n * 32 + d - 96]; pv = po[n * 32 + d - 96]; }
            OA[n * 136 + d] = f2bf(sv);
            OP[n * 136 + d] = f2bf(pv);
        }
    }
    __syncthreads();

    // ---- PA: wv0-7: va->VAr, delta->TD ; wv8-15: q->QL, k->KL ----
    if (wv < 8) {
        int mt = wv & 1, ntA = wv >> 1, ntB = ntA + 4;
        f32x4 va0 = Z, va1 = Z, vp0 = Z, vp1 = Z;
#pragma unroll
        for (int kt = 0; kt < 4; ++kt) {
            bf16x8 aA = afrag(OA, 136, mt * 16, kt);
            bf16x8 aP = afrag(OP, 136, mt * 16, kt);
            bf16x8 b0 = bfrag_pk(pk + PK_WV, 8, kt, ntA);
            bf16x8 b1 = bfrag_pk(pk + PK_WV, 8, kt, ntB);
            va0 = MFMA(aA, b0, va0); va1 = MFMA(aA, b1, va1);
            vp0 = MFMA(aP, b0, vp0); vp1 = MFMA(aP, b1, vp1);
        }
#pragma unroll
        for (int r = 0; r < 4; ++r) {
            int row = mt * 16 + quad * 4 + r;
            float tva0 = fast_tanh(va0[r]), tvp0 = fast_tanh(vp0[r]);
            float tva1 = fast_tanh(va1[r]), tvp1 = fast_tanh(vp1[r]);
            VAr[row * 136 + ntA * 16 + l16] = f2bf(tva0);
            VAr[row * 136 + ntB * 16 + l16] = f2bf(tva1);
            TD[row * 136 + ntA * 16 + l16] = f2bf(tvp0 - tva0);
            TD[row * 136 + ntB * 16 + l16] = f2bf(tvp1 - tva1);
        }
    } else {
        int s = wv - 8;
        int mt = s & 1, pb2 = s >> 1;                      // 0..3
        bf16x8 afr[4];
#pragma unroll
        for (int kt = 0; kt < 4; ++kt) afr[kt] = afrag(OA, 136, mt * 16, kt);
#pragma unroll
        for (int m2 = 0; m2 < 2; ++m2) {
            const unsigned short* pkM = pk + (m2 ? PK_WK : PK_WQ);
            unsigned short* dst = m2 ? KL : QL;
#pragma unroll
            for (int h = 0; h < 2; ++h) {
                int nt = pb2 + h * 4;
                f32x4 acc = Z;
#pragma unroll
                for (int kt = 0; kt < 4; ++kt)
                    acc = MFMA(afr[kt], bfrag_pk(pkM, 8, kt, nt), acc);
#pragma unroll
                for (int r = 0; r < 4; ++r)
                    dst[(mt * 16 + quad * 4 + r) * 136 + nt * 16 + l16] = f2bf(acc[r]);
            }
        }
    }
    __syncthreads();

    // ---- PB: wv0-7: G (regs) + VA1 (shared Wf1 B-frags); wv8-11: scores;
    //          wv12-15: oap -> OP ----
    f32x4 gReg = Z;
    int gmt = 0, gnt = 0;
    if (wv < 8) {
        gmt = wv & 1; gnt = wv >> 1;                       // G,VA1: 8 tiles 32x64
        f32x4 v1 = Z;
#pragma unroll
        for (int kt = 0; kt < 4; ++kt) {
            bf16x8 bw = bfrag_pk(pk + PK_WF1, 4, kt, gnt);
            gReg = MFMA(afrag(TD, 136, gmt * 16, kt), bw, gReg);
            v1   = MFMA(afrag(VAr, 136, gmt * 16, kt), bw, v1);
        }
#pragma unroll
        for (int r = 0; r < 4; ++r)
            VA1T[(gnt * 16 + l16) * 40 + gmt * 16 + quad * 4 + r] = f2bf(v1[r]);
    } else if (wv < 12) {
        int s = wv - 8;
        int mt = s & 1, nt = s >> 1;
        f32x4 acc = Z;
#pragma unroll
        for (int kt = 0; kt < 4; ++kt)
            acc = MFMA(afrag(QL, 136, mt * 16, kt), afrag(KL, 136, nt * 16, kt), acc);
        // D[m=j][n=a] -> SB1[a][j]
#pragma unroll
        for (int r = 0; r < 4; ++r)
            SB1[(nt * 16 + l16) * 40 + mt * 16 + quad * 4 + r] = f2bf(acc[r]);
    } else {
        const float* st = states_p  + (size_t)b * 3072;
        const float* ac = actions_p + (size_t)b * 1024;
        int t256 = tid - 768;
#pragma unroll
        for (int k = 0; k < 16; ++k) {
            int idx = t256 + k * 256;
            int n = idx >> 7, d = idx & 127;
            OP[n * 136 + d] = f2bf((d < 96) ? st[n * 96 + d] : ac[n * 32 + d - 96]);
        }
    }
    __syncthreads();

    // ---- PC: all waves: qp->QL, kp->KL, avp->AVr (row-major) ----
    {
        int mt = wv & 1, nt = wv >> 1;                     // nt 0..7
        bf16x8 ao[4], ap[4];
#pragma unroll
        for (int kt = 0; kt < 4; ++kt) {
            ao[kt] = afrag(OA, 136, mt * 16, kt);
            ap[kt] = afrag(OP, 136, mt * 16, kt);
        }
        f32x4 aq = Z, akp = Z, aav = Z;
#pragma unroll
        for (int kt = 0; kt < 4; ++kt) {
            aq  = MFMA(ao[kt], bfrag_pk(pk + PK_WQP, 8, kt, nt), aq);
            akp = MFMA(ap[kt], bfrag_pk(pk + PK_WKP, 8, kt, nt), akp);
            aav = MFMA(ap[kt], bfrag_pk(pk + PK_WVP, 8, kt, nt), aav);
        }
#pragma unroll
        for (int r = 0; r < 4; ++r) {
            int row = mt * 16 + quad * 4 + r;
            QL[row * 136 + nt * 16 + l16] = f2bf(aq[r]);
            KL[row * 136 + nt * 16 + l16] = f2bf(akp[r]);
            AVr[row * 136 + nt * 16 + l16] = f2bf(fast_tanh(aav[r]));
        }
    }
    __syncthreads();

    // ---- PD: wv0-3: scores_p->SB2; wv4-11: AV1 = avp@Wf1_bot -> AV1T;
    //          wv12-15: weight softmax (SB1 in-place + export) ----
    if (wv < 4) {
        int mt = wv & 1, nt = wv >> 1;
        f32x4 acc = Z;
#pragma unroll
        for (int kt = 0; kt < 4; ++kt)
            acc = MFMA(afrag(QL, 136, mt * 16, kt), afrag(KL, 136, nt * 16, kt), acc);
        // D[m=n][n'=p] -> SB2[p][n]
#pragma unroll
        for (int r = 0; r < 4; ++r)
            SB2[(nt * 16 + l16) * 40 + mt * 16 + quad * 4 + r] = f2bf(acc[r]);
    } else if (wv < 12) {
        int s = wv - 4;
        int amt = s & 1, ant = s >> 1;                     // p-tile, h-tile
        f32x4 av1 = Z;
#pragma unroll
        for (int kt = 0; kt < 4; ++kt)
            av1 = MFMA(afrag(AVr, 136, amt * 16, kt),
                       bfrag_pk(pk + PK_WF1, 4, kt + 4, ant), av1);
#pragma unroll
        for (int r = 0; r < 4; ++r)
            AV1T[(ant * 16 + l16) * 40 + amt * 16 + quad * 4 + r] = f2bf(av1[r]);
    } else {
        int t256 = tid - 768;
#pragma unroll
        for (int rep = 0; rep < 4; ++rep) {
            int idx = t256 + rep * 256;
            int j = idx & 31, a = idx >> 5;
            float x = bf2f(SB1[a * 40 + j]);               // scale pre-folded
            float m = x;
#pragma unroll
            for (int msk = 16; msk >= 1; msk >>= 1) m = fmaxf(m, __shfl_xor(m, msk));
            float e = __expf(x - m);
            float s = e;
#pragma unroll
            for (int msk = 16; msk >= 1; msk >>= 1) s += __shfl_xor(s, msk);
            float w = e / s;
            out[W_OFF + (size_t)b * 1024 + a * 32 + j] = w;
            SB1[a * 40 + j] = f2bf(w);
        }
    }
    __syncthreads();

    // ---- PE: wv0-3: wp softmax (SB2->WPB + export); wv8-15: F1=weight@VA1 ----
    f32x4 f1 = Z;
    int fmt = 0, fnt = 0;
    if (wv < 4) {
#pragma unroll
        for (int rep = 0; rep < 4; ++rep) {
            int idx = tid + rep * 256;
            int n = idx & 31, p = idx >> 5;
            float x = bf2f(SB2[p * 40 + n]);               // scale pre-folded
            float m = x;
#pragma unroll
            for (int msk = 16; msk >= 1; msk >>= 1) m = fmaxf(m, __shfl_xor(m, msk));
            float e = __expf(x - m);
            float s = e;
#pragma unroll
            for (int msk = 16; msk >= 1; msk >>= 1) s += __shfl_xor(s, msk);
            float w2 = e / s;
            out[WP_OFF + (size_t)b * 1024 + n * 32 + p] = w2;
            WPB[n * 40 + p] = f2bf(w2);
        }
    } else if (wv >= 8) {
        int s = wv - 8;
        fmt = s & 1; fnt = s >> 1;                         // a-tile, h-tile
        f1 = MFMA(afrag(SB1, 40, fmt * 16, 0), afrag(VA1T, 40, fnt * 16, 0), Z);
    }
    __syncthreads();

    // ---- PF: wv0-7: park gReg -> GP; wv8-15: F += wp@AV1 -> FP ----
    if (wv < 8) {
#pragma unroll
        for (int r = 0; r < 4; ++r)
            GP[(gmt * 16 + quad * 4 + r) * 67 + gnt * 16 + l16] = gReg[r];
    } else {
        f1 = MFMA(afrag(WPB, 40, fmt * 16, 0), afrag(AV1T, 40, fnt * 16, 0), f1);
#pragma unroll
        for (int r = 0; r < 4; ++r)
            FP[(fmt * 16 + quad * 4 + r) * 66 + fnt * 16 + l16] = f1[r] * invN;
    }
    __syncthreads();

    // ---- Epilogue: value tiles via MFMA; h built in-register (A-frag order)
    {
        bf16x8 bw[2][2];
#pragma unroll
        for (int kt = 0; kt < 2; ++kt)
#pragma unroll
            for (int nt = 0; nt < 2; ++nt)
                bw[kt][nt] = bfrag_pk(pk + PK_WF2, 2, kt, nt);

#pragma unroll
        for (int t4 = 0; t4 < 4; ++t4) {
            int tile = wv + t4 * 16;                       // 0..63
            int m0 = tile * 16;
            int a = m0 >> 5;
            int i = (m0 & 31) + l16;
            float w = bf2f(SB1[a * 40 + i]) * invN;
            const float* Fa = FP + a * 66;
            const float* Gi = GP + i * 67;
            f32x4 acc0 = Z, acc1 = Z;
#pragma unroll
            for (int kt = 0; kt < 2; ++kt) {
                union { unsigned short u[8]; bf16x8 v; } h;
                int dbase = kt * 32 + quad * 8;
#pragma unroll
                for (int j = 0; j < 8; ++j) {
                    float z = fmaf(w, Gi[dbase + j], Fa[dbase + j]);
                    z = fmaxf(z, 0.01f * z);               // leaky_relu
                    h.u[j] = f2bf(z);
                }
                acc0 = MFMA(h.v, bw[kt][0], acc0);
                acc1 = MFMA(h.v, bw[kt][1], acc1);
            }
            float* base = out + (size_t)b * 32768 + (size_t)m0 * 32;
#pragma unroll
            for (int r = 0; r < 4; ++r) {
                int row = quad * 4 + r;
                base[row * 32 + l16]      = acc0[r];
                base[row * 32 + 16 + l16] = acc1[r];
            }
        }
    }
}

// ---------------------------------------------------------------------------
extern "C" void kernel_launch(void* const* d_in, const int* in_sizes, int n_in,
                              void* d_out, int out_size, void* d_ws, size_t ws_size,
                              hipStream_t stream)
{
    const float* states    = (const float*)d_in[0];
    const float* policies  = (const float*)d_in[1];
    const float* actions   = (const float*)d_in[2];
    const float* states_p  = (const float*)d_in[3];
    const float* actions_p = (const float*)d_in[4];
    const float* Wk        = (const float*)d_in[5];
    const float* Wq        = (const float*)d_in[6];
    const float* Wv        = (const float*)d_in[7];
    const float* Wkp       = (const float*)d_in[8];
    const float* Wqp       = (const float*)d_in[9];
    const float* Wvp       = (const float*)d_in[10];
    const float* Wf1       = (const float*)d_in[11];
    const float* Wf2       = (const float*)d_in[12];
    float* out = (float*)d_out;
    unsigned short* pk = (unsigned short*)d_ws;

    pack_lite<<<57, 256, 0, stream>>>(Wk, Wq, Wv, Wkp, Wqp, Wvp, Wf1, Wf2, pk);
    critic_fused<<<256, 1024, 0, stream>>>(states, policies, actions,
                                           states_p, actions_p, pk, out);
}